// Round 12
// baseline (9288.699 us; speedup 1.0000x reference)
//
#include <hip/hip_runtime.h>
#include <cstdint>
#include <cstddef>

typedef unsigned long long ull;

#define N_PTS  32768
#define NP1    2048
#define NSAMP1 32
#define NP2    512
#define NSAMP2 64
#define NCELL  4096

// ---------------- prep: xyz = points - [x,y,0], SoA ----------------
__global__ __launch_bounds__(256) void k_prep(const float* __restrict__ pts,
                                              const float* __restrict__ prop,
                                              float* __restrict__ xx,
                                              float* __restrict__ xy,
                                              float* __restrict__ xz) {
  int t = blockIdx.x * 256 + threadIdx.x;
  if (t >= N_PTS) return;
  float x = prop[0], y = prop[1];
  xx[t] = __fsub_rn(pts[3 * t + 0], x);
  xy[t] = __fsub_rn(pts[3 * t + 1], y);
  xz[t] = pts[3 * t + 2];
}

// ---------------- spatial sort preprocess (for wave-pruned FPS1) ----------------
// 16^3 Morton cells over [-4.5,4.5)^3. Intra-cell order nondeterministic
// (atomicAdd) but FPS output invariant: winner picked by atomicMin over keys
// whose HIGH bits are the ORIGINAL index (= jnp.argmax first-max semantics).
// Measured in R7: sort kernels cheap (<100us), absmax=0 with sorted fps.
__device__ __forceinline__ int spread3(int v) {
  return (v & 1) | ((v & 2) << 2) | ((v & 4) << 4) | ((v & 8) << 6);
}

__global__ __launch_bounds__(256) void k_zerocells(int* __restrict__ cellh) {
  int t = blockIdx.x * 256 + threadIdx.x;
  if (t < NCELL) cellh[t] = 0;
}

__global__ __launch_bounds__(256) void k_cell(const float* __restrict__ xx,
                                              const float* __restrict__ xy,
                                              const float* __restrict__ xz,
                                              int* __restrict__ cellid,
                                              int* __restrict__ cellh) {
  int t = blockIdx.x * 256 + threadIdx.x;
  if (t >= N_PTS) return;
  const float sc = 16.0f / 9.0f;
  int xi = (int)((xx[t] + 4.5f) * sc); xi = xi < 0 ? 0 : (xi > 15 ? 15 : xi);
  int yi = (int)((xy[t] + 4.5f) * sc); yi = yi < 0 ? 0 : (yi > 15 ? 15 : yi);
  int zi = (int)((xz[t] + 4.5f) * sc); zi = zi < 0 ? 0 : (zi > 15 ? 15 : zi);
  int c = spread3(xi) | (spread3(yi) << 1) | (spread3(zi) << 2);
  cellid[t] = c;
  atomicAdd(&cellh[c], 1);
}

// exclusive scan of 4096 ints: 1024 threads x 4 vals, wave shfl scan + LDS
__global__ __launch_bounds__(1024) void k_scan(const int* __restrict__ h,
                                               int* __restrict__ o) {
  __shared__ int wsum[16];
  int tid = threadIdx.x;
  int4 v = *(const int4*)&h[tid * 4];
  int s = v.x + v.y + v.z + v.w;
  int lane = tid & 63;
  int incl = s;
#pragma unroll
  for (int m = 1; m < 64; m <<= 1) {
    int n = __shfl_up(incl, m, 64);
    if (lane >= m) incl += n;
  }
  if (lane == 63) wsum[tid >> 6] = incl;
  __syncthreads();
  int woff = 0;
  for (int w = 0; w < (tid >> 6); ++w) woff += wsum[w];
  int excl = woff + incl - s;
  int4 out;
  out.x = excl;
  out.y = excl + v.x;
  out.z = out.y + v.y;
  out.w = out.z + v.z;
  *(int4*)&o[tid * 4] = out;
}

__global__ __launch_bounds__(256) void k_scatter(const float* __restrict__ xx,
                                                 const float* __restrict__ xy,
                                                 const float* __restrict__ xz,
                                                 const int* __restrict__ cellid,
                                                 int* __restrict__ cello,
                                                 float* __restrict__ spx,
                                                 float* __restrict__ spy,
                                                 float* __restrict__ spz,
                                                 int* __restrict__ perm) {
  int t = blockIdx.x * 256 + threadIdx.x;
  if (t >= N_PTS) return;
  int pos = atomicAdd(&cello[cellid[t]], 1);
  spx[pos] = xx[t];
  spy[pos] = xy[t];
  spz[pos] = xz[t];
  perm[pos] = t;
}

// ---------------- FPS1: 2048 of 32768, single block, WAVE-uniform pruning ----------------
// R12 = R4's measured structure (4558us: 2-barrier reduce, wmax array,
// atomicMin double-buffered S) + the R7-proven bbox skip, moved to WAVE
// granularity and with every R7/R8 failure mode fixed:
//  - centroid coords read from spx/spy/spz = bulk-read at init -> L2-warm
//    (R7 regressed on cold xx[f] HBM misses; FETCH 531KB -> ~500KB now);
//  - skip decided per-wave from a wave-shfl-reduced bbox -> wave-uniform
//    branch, no divergence, NO extra barrier (R8 had 3 barriers);
//  - per-thread pbest persists across skipped iters so argmax rescan stays
//    correct for skipped waves.
// Winner key = origIdx<<15 | sortedIdx (30 bits): atomicMin -> smallest
// ORIGINAL index among bitwise-max holders (= jnp.argmax first-max, exact),
// low bits give the sorted position for warm coord loads. Skip is exact:
// lb*0.999 >= wbmax => computed d2 >= d[s] for all s (margin >> 4-ulp slop;
// same proof as R7, which passed absmax=0). 1024 thr x 32 Morton-consecutive
// pts (thread-major so wave w owns sorted [w*2048,(w+1)*2048) -> tight bbox);
// z in LDS (128KB, chunk-XOR swizzle, conflict-free b128); px/py/d in
// regs+AGPR (64-VGPR cap, same as R4's measured update path).
#define F1T 1024
#define F1P 32

__global__
__attribute__((amdgpu_flat_work_group_size(F1T, F1T)))
void k_fps1(const float* __restrict__ spx,
            const float* __restrict__ spy,
            const float* __restrict__ spz,
            const int* __restrict__ perm,
            float* __restrict__ ox,
            float* __restrict__ oy,
            float* __restrict__ oz) {
  __shared__ __align__(16) float zl[F1P * F1T];   // 128 KB, swizzled row-per-thread
  __shared__ float wmax[F1T / 64];                // 16 per-wave maxima
  __shared__ int S[2];                            // double-buffered winner key
  int tid = threadIdx.x;
  char* zb = (char*)zl;
  int rowb = tid * 128 + (tid & 7) * 16;          // swizzle folded into row base
  int base = tid * F1P;                           // thread-major: wave owns 2048 contig
  float px[F1P], py[F1P], d[F1P];
  float lox = 1e30f, hix = -1e30f, loy = 1e30f, hiy = -1e30f, loz = 1e30f, hiz = -1e30f;
  if (tid == 0) S[1] = 0x7fffffff;
#pragma unroll
  for (int q = 0; q < 8; ++q) {
    float4 vx = *(const float4*)&spx[base + q * 4];
    float4 vy = *(const float4*)&spy[base + q * 4];
    float4 vz = *(const float4*)&spz[base + q * 4];
    int4   vp = *(const int4*)&perm[base + q * 4];
    *(float4*)(zb + (rowb ^ (q * 16))) = vz;      // ds_write_b128, swizzled
    float fx[4] = {vx.x, vx.y, vx.z, vx.w};
    float fy[4] = {vy.x, vy.y, vy.z, vy.w};
    float fz[4] = {vz.x, vz.y, vz.z, vz.w};
    int   ip[4] = {vp.x, vp.y, vp.z, vp.w};
#pragma unroll
    for (int j = 0; j < 4; ++j) {
      int s = q * 4 + j;
      px[s] = fx[j]; py[s] = fy[j]; d[s] = 1e10f;
      lox = fminf(lox, fx[j]); hix = fmaxf(hix, fx[j]);
      loy = fminf(loy, fy[j]); hiy = fmaxf(hiy, fy[j]);
      loz = fminf(loz, fz[j]); hiz = fmaxf(hiz, fz[j]);
      if (ip[j] == 0) S[0] = base + s;            // key: orig0<<15 | sorted = sorted
    }
  }
  // wave-wide bbox (all lanes converge to identical values)
#pragma unroll
  for (int m = 1; m < 64; m <<= 1) {
    lox = fminf(lox, __shfl_xor(lox, m, 64)); hix = fmaxf(hix, __shfl_xor(hix, m, 64));
    loy = fminf(loy, __shfl_xor(loy, m, 64)); hiy = fmaxf(hiy, __shfl_xor(hiy, m, 64));
    loz = fminf(loz, __shfl_xor(loz, m, 64)); hiz = fmaxf(hiz, __shfl_xor(hiz, m, 64));
  }
  float pbest = 1e10f, wbmax = 1e10f;
  __syncthreads();
  for (int it = 0; it < NP1; ++it) {
    int fs = __builtin_amdgcn_readfirstlane(S[it & 1] & 32767);  // sorted idx
    float cx = spx[fs], cy = spy[fs], cz = spz[fs];              // L2-warm scalar loads
    if (tid == 0) { ox[it] = cx; oy[it] = cy; oz[it] = cz; }
    // conservative lower bound dist^2(centroid -> wave bbox); wave-uniform
    float tx = fmaxf(fmaxf(__fsub_rn(lox, cx), __fsub_rn(cx, hix)), 0.0f);
    float ty = fmaxf(fmaxf(__fsub_rn(loy, cy), __fsub_rn(cy, hiy)), 0.0f);
    float tz = fmaxf(fmaxf(__fsub_rn(loz, cz), __fsub_rn(cz, hiz)), 0.0f);
    float lb = __fadd_rn(__fadd_rn(__fmul_rn(tx, tx), __fmul_rn(ty, ty)), __fmul_rn(tz, tz));
    if (__fmul_rn(lb, 0.999f) < wbmax) {          // wave-uniform; else no d changes
      float nb = -1.0f;
#pragma unroll
      for (int c = 0; c < 8; ++c) {
        const float4 zz = *(const float4*)(zb + (rowb ^ (c * 16)));  // ds_read_b128
        float zv[4] = {zz.x, zz.y, zz.z, zz.w};
#pragma unroll
        for (int j = 0; j < 4; ++j) {
          int s = c * 4 + j;
          // exact reference arithmetic: no fma, (dx^2 + dy^2) + dz^2
          float dx = __fsub_rn(px[s], cx);
          float dy = __fsub_rn(py[s], cy);
          float dz = __fsub_rn(zv[j], cz);
          float d2 = __fadd_rn(__fadd_rn(__fmul_rn(dx, dx), __fmul_rn(dy, dy)), __fmul_rn(dz, dz));
          float dn = fminf(d[s], d2);
          d[s] = dn;
          nb = fmaxf(nb, dn);
        }
      }
      pbest = nb;
      float wv = nb;
#pragma unroll
      for (int m = 1; m < 64; m <<= 1) wv = fmaxf(wv, __shfl_xor(wv, m, 64));
      wbmax = wv;
    }
    if ((tid & 63) == 0) wmax[tid >> 6] = wbmax;
    __syncthreads();                              // (A) wmax ready; reads of S done
    float gb = wmax[0];
#pragma unroll
    for (int k = 1; k < F1T / 64; ++k) gb = fmaxf(gb, wmax[k]);
    if (pbest == gb) {                            // only global-max holders rescan
      int cand = 0x7fffffff;
#pragma unroll
      for (int s = 0; s < F1P; ++s)
        if (d[s] == gb) {
          int key = (perm[base + s] << 15) | (base + s);   // orig<<15 | sorted
          cand = cand < key ? cand : key;
        }
      atomicMin(&S[(it + 1) & 1], cand);          // min orig idx = first-max
    }
    if (tid == 0) S[it & 1] = 0x7fffffff;         // reset: becomes dst at it+1
    __syncthreads();                              // (B) winner final
  }
}

// ---------------- FPS2: 512 of 2048, single block, 512 threads x 4 pts ----------------
#define F2T 512
#define F2P 4
__global__ __launch_bounds__(F2T, 1) void k_fps2(const float* __restrict__ x1x,
                                                 const float* __restrict__ x1y,
                                                 const float* __restrict__ x1z,
                                                 float* __restrict__ ox,
                                                 float* __restrict__ oy,
                                                 float* __restrict__ oz) {
  __shared__ float sx[NP1], sy[NP1], sz[NP1];   // 24 KB: centroid reads become LDS broadcast
  __shared__ float wmax[F2T / 64];
  __shared__ int S[2];
  int tid = threadIdx.x;
  float px[F2P], py[F2P], pz[F2P], d[F2P];
#pragma unroll
  for (int s = 0; s < F2P; ++s) {
    int i = s * F2T + tid;
    px[s] = x1x[i]; py[s] = x1y[i]; pz[s] = x1z[i];
    sx[i] = px[s];  sy[i] = py[s];  sz[i] = pz[s];
    d[s] = 1e10f;
  }
  if (tid == 0) { S[0] = 0; S[1] = 0x7fffffff; }
  __syncthreads();
  for (int it = 0; it < NP2; ++it) {
    int f = __builtin_amdgcn_readfirstlane(S[it & 1]);
    float cx = sx[f], cy = sy[f], cz = sz[f];  // LDS broadcast
    if (tid == 0) { ox[it] = cx; oy[it] = cy; oz[it] = cz; }
    float bestv = -1.0f;
#pragma unroll
    for (int s = 0; s < F2P; ++s) {
      float dx = __fsub_rn(px[s], cx);
      float dy = __fsub_rn(py[s], cy);
      float dz = __fsub_rn(pz[s], cz);
      float d2 = __fadd_rn(__fadd_rn(__fmul_rn(dx, dx), __fmul_rn(dy, dy)), __fmul_rn(dz, dz));
      float dn = fminf(d[s], d2);
      d[s] = dn;
      bestv = fmaxf(bestv, dn);
    }
    float wv = bestv;
#pragma unroll
    for (int m = 1; m < 64; m <<= 1) wv = fmaxf(wv, __shfl_xor(wv, m, 64));
    if ((tid & 63) == 0) wmax[tid >> 6] = wv;
    __syncthreads();                         // (A)
    float gb = wmax[0];
#pragma unroll
    for (int k = 1; k < F2T / 64; ++k) gb = fmaxf(gb, wmax[k]);
    if (bestv == gb) {
      int cand = 0x7fffffff;
#pragma unroll
      for (int s = F2P - 1; s >= 0; --s) cand = (d[s] == gb) ? (s * F2T + tid) : cand;
      atomicMin(&S[(it + 1) & 1], cand);
    }
    if (tid == 0) S[it & 1] = 0x7fffffff;
    __syncthreads();                         // (B)
  }
}

// ---------------- ball query: first ns indices (ascending) within r2, pad with first ----------------
__global__ void k_ballq(const float* __restrict__ px, const float* __restrict__ py,
                        const float* __restrict__ pz, int n,
                        const float* __restrict__ qx, const float* __restrict__ qy,
                        const float* __restrict__ qz, int S,
                        float r2, int ns, int* __restrict__ out) {
  int w = (blockIdx.x * (int)blockDim.x + threadIdx.x) >> 6;  // one wave per query
  int lane = threadIdx.x & 63;
  if (w >= S) return;
  float cx = qx[w], cy = qy[w], cz = qz[w];
  int found = 0, first = 0;
  bool havefirst = false;
  for (int base = 0; base < n && found < ns; base += 64) {
    int i = base + lane;
    float dx = __fsub_rn(px[i], cx);
    float dy = __fsub_rn(py[i], cy);
    float dz = __fsub_rn(pz[i], cz);
    float d2 = __fadd_rn(__fadd_rn(__fmul_rn(dx, dx), __fmul_rn(dy, dy)), __fmul_rn(dz, dz));
    bool isin = d2 <= r2;
    ull m = __ballot(isin);
    if (!havefirst && m != 0ull) { first = base + __builtin_ctzll(m); havefirst = true; }
    if (isin) {
      int r = (int)__popcll(m & ((1ull << lane) - 1ull));
      int slot = found + r;
      if (slot < ns) out[w * ns + slot] = i;
    }
    found += (int)__popcll(m);
  }
  for (int s2 = found + lane; s2 < ns; s2 += 64) out[w * ns + s2] = first;
}

// ---------------- gather SA1 input rows (15 ch) ----------------
__global__ __launch_bounds__(256) void k_gather1(const float* __restrict__ pts,
                                                 const float* __restrict__ prop,
                                                 const float* __restrict__ xx,
                                                 const float* __restrict__ xy,
                                                 const float* __restrict__ xz,
                                                 const float* __restrict__ x1x,
                                                 const float* __restrict__ x1y,
                                                 const float* __restrict__ x1z,
                                                 const int* __restrict__ gidx,
                                                 float* __restrict__ X, int rbase) {
  int rl = blockIdx.x * 256 + threadIdx.x;
  if (rl >= 8192) return;
  int r = rbase + rl;
  int s = r >> 5;
  int g = gidx[r];
  float x = prop[0], y = prop[1], wz = prop[3];
  float w2 = wz * 0.5f;  // == w/2 exactly
  float oxp = __fadd_rn(x, w2), oxm = __fsub_rn(x, w2);
  float oyp = __fadd_rn(y, w2), oym = __fsub_rn(y, w2);
  float gx = xx[g], gy = xy[g], gz = xz[g];
  float pxv = pts[3 * g + 0], pyv = pts[3 * g + 1];
  float* o = X + (size_t)rl * 15;
  o[0] = __fsub_rn(gx, x1x[s]);
  o[1] = __fsub_rn(gy, x1y[s]);
  o[2] = __fsub_rn(gz, x1z[s]);
  o[3] = __fsub_rn(pxv, oxp);  o[4]  = gy;                    o[5]  = gz;
  o[6] = __fsub_rn(pxv, oxm);  o[7]  = gy;                    o[8]  = gz;
  o[9] = gx;                   o[10] = __fsub_rn(pyv, oyp);   o[11] = gz;
  o[12] = gx;                  o[13] = __fsub_rn(pyv, oym);   o[14] = gz;
}

// ---------------- gather SA2 input rows (131 ch), element-parallel ----------------
__global__ __launch_bounds__(256) void k_gather2(const float* __restrict__ x1x,
                                                 const float* __restrict__ x1y,
                                                 const float* __restrict__ x1z,
                                                 const float* __restrict__ x2x,
                                                 const float* __restrict__ x2y,
                                                 const float* __restrict__ x2z,
                                                 const int* __restrict__ gidx,
                                                 const float* __restrict__ f1,
                                                 float* __restrict__ X, int rbase) {
  int e = blockIdx.x * 256 + threadIdx.x;
  if (e >= 8192 * 131) return;
  int rl = e / 131, c = e % 131;
  int r = rbase + rl;
  int s = r >> 6;
  int g = gidx[r];
  float v;
  if (c == 0)      v = __fsub_rn(x1x[g], x2x[s]);
  else if (c == 1) v = __fsub_rn(x1y[g], x2y[s]);
  else if (c == 2) v = __fsub_rn(x1z[g], x2z[s]);
  else             v = f1[(size_t)g * 128 + (c - 3)];
  X[e] = v;
}

// ---------------- gather SA3 input rows (259 ch) ----------------
__global__ __launch_bounds__(256) void k_gather3(const float* __restrict__ x2x,
                                                 const float* __restrict__ x2y,
                                                 const float* __restrict__ x2z,
                                                 const float* __restrict__ f2,
                                                 float* __restrict__ X) {
  int e = blockIdx.x * 256 + threadIdx.x;
  if (e >= 512 * 259) return;
  int rl = e / 259, c = e % 259;
  float v;
  if (c == 0)      v = x2x[rl];
  else if (c == 1) v = x2y[rl];
  else if (c == 2) v = x2z[rl];
  else             v = f2[(size_t)rl * 256 + (c - 3)];
  X[e] = v;
}

// ---------------- relu GEMM: C[m][n] = relu(bias[n] + sum_k A[m,k]*W[n,k]) ----------------
// 64x64 tile, 256 threads, 4x4 per thread, transposed LDS staging for b128 reads
__global__ __launch_bounds__(256) void k_gemm(const float* __restrict__ A,
                                              const float* __restrict__ W,
                                              const float* __restrict__ bias,
                                              float* __restrict__ C,
                                              int M, int N, int K) {
  __shared__ __align__(16) float As[16][68];
  __shared__ __align__(16) float Bs[16][68];
  int tid = threadIdx.x;
  int bn = blockIdx.x * 64, bm = blockIdx.y * 64;
  int tx = tid & 15, ty = tid >> 4;
  float acc[4][4] = {{0.f, 0.f, 0.f, 0.f}, {0.f, 0.f, 0.f, 0.f},
                     {0.f, 0.f, 0.f, 0.f}, {0.f, 0.f, 0.f, 0.f}};
  for (int k0 = 0; k0 < K; k0 += 16) {
#pragma unroll
    for (int e = 0; e < 4; ++e) {
      int flat = tid + e * 256;
      int rr = flat >> 4, cc = flat & 15;
      As[cc][rr] = (k0 + cc < K) ? A[(size_t)(bm + rr) * K + (k0 + cc)] : 0.0f;
      Bs[cc][rr] = (k0 + cc < K) ? W[(size_t)(bn + rr) * K + (k0 + cc)] : 0.0f;
    }
    __syncthreads();
#pragma unroll
    for (int kk = 0; kk < 16; ++kk) {
      const float4 a = *(const float4*)&As[kk][ty * 4];
      const float4 b = *(const float4*)&Bs[kk][tx * 4];
      float av[4] = {a.x, a.y, a.z, a.w};
      float bb[4] = {b.x, b.y, b.z, b.w};
#pragma unroll
      for (int i = 0; i < 4; ++i)
#pragma unroll
        for (int j = 0; j < 4; ++j)
          acc[i][j] = fmaf(av[i], bb[j], acc[i][j]);
    }
    __syncthreads();
  }
#pragma unroll
  for (int i = 0; i < 4; ++i) {
    int m = bm + ty * 4 + i;
    float4 o;
    o.x = fmaxf(acc[i][0] + bias[bn + tx * 4 + 0], 0.0f);
    o.y = fmaxf(acc[i][1] + bias[bn + tx * 4 + 1], 0.0f);
    o.z = fmaxf(acc[i][2] + bias[bn + tx * 4 + 2], 0.0f);
    o.w = fmaxf(acc[i][3] + bias[bn + tx * 4 + 3], 0.0f);
    *(float4*)&C[(size_t)m * N + bn + tx * 4] = o;
  }
}

// ---------------- maxpool over Ks consecutive rows ----------------
__global__ __launch_bounds__(256) void k_maxpool(const float* __restrict__ H,
                                                 float* __restrict__ F,
                                                 int S, int Ks, int Nch, int sbase) {
  int t = blockIdx.x * 256 + threadIdx.x;
  if (t >= S * Nch) return;
  int sl = t / Nch, n = t % Nch;
  const float* p = H + (size_t)sl * Ks * Nch + n;
  float m = p[0];
  for (int k = 1; k < Ks; ++k) m = fmaxf(m, p[(size_t)k * Nch]);
  F[(size_t)(sbase + sl) * Nch + n] = m;
}

// ---------------- host ----------------
extern "C" void kernel_launch(void* const* d_in, const int* in_sizes, int n_in,
                              void* d_out, int out_size, void* d_ws, size_t ws_size,
                              hipStream_t stream) {
  (void)n_in; (void)out_size; (void)ws_size;
  const float* pts = (const float*)d_in[0];
  const float* prop = (const float*)d_in[1];

  // inputs may arrive in dict order (w0,b0,w1,b1,w2,b2) or signature order (w0,w1,w2,b0,b1,b2)
  bool dict_order = (in_sizes[3] == 64);
  const float *w[3][3], *b[3][3];
  for (int g = 0; g < 3; ++g)
    for (int l = 0; l < 3; ++l) {
      int base = 2 + g * 6;
      int wi = dict_order ? (base + l * 2) : (base + l);
      int bi = dict_order ? (base + l * 2 + 1) : (base + 3 + l);
      w[g][l] = (const float*)d_in[wi];
      b[g][l] = (const float*)d_in[bi];
    }

  float* ws = (float*)d_ws;
  float* xx = ws;
  float* xy = xx + N_PTS;
  float* xz = xy + N_PTS;
  float* x1x = xz + N_PTS;
  float* x1y = x1x + NP1;
  float* x1z = x1y + NP1;
  float* x2x = x1z + NP1;
  float* x2y = x2x + NP2;
  float* x2z = x2y + NP2;
  int* gidx1 = (int*)(x2z + NP2);            // 2048*32
  int* gidx2 = gidx1 + NP1 * NSAMP1;         // 512*64
  float* f1 = (float*)(gidx2 + NP2 * NSAMP2);// 2048*128
  float* f2 = f1 + NP1 * 128;                // 512*256
  float* Xp = f2 + NP2 * 256;                // 8192*131 pool (also 8192*15, 512*259)
  float* Ha = Xp + 8192 * 131;               // 8192*128 pool
  float* Hb = Ha + 8192 * 128;               // 8192*128 pool
  float* Hc = Hb + 8192 * 128;               // 8192*256 pool (also 512*1024)

  // sort scratch carved from the Xp pool (free until k_gather1 runs)
  int*   cellid = (int*)Xp;                  // 32768
  int*   cellh  = cellid + N_PTS;            // 4096
  int*   cello  = cellh + NCELL;             // 4096
  int*   perm   = cello + NCELL;             // 32768
  float* spx    = (float*)(perm + N_PTS);    // 32768
  float* spy    = spx + N_PTS;               // 32768
  float* spz    = spy + N_PTS;               // 32768  (total 172K ints << Xp pool)

  const float R2A = (float)(0.4 * 0.4);  // f32 of python-f64 product: 1 ulp below 0.4f*0.4f
  const float R2B = (float)(0.8 * 0.8);

  k_prep<<<128, 256, 0, stream>>>(pts, prop, xx, xy, xz);
  k_zerocells<<<16, 256, 0, stream>>>(cellh);
  k_cell<<<128, 256, 0, stream>>>(xx, xy, xz, cellid, cellh);
  k_scan<<<1, 1024, 0, stream>>>(cellh, cello);
  k_scatter<<<128, 256, 0, stream>>>(xx, xy, xz, cellid, cello, spx, spy, spz, perm);
  k_fps1<<<1, F1T, 0, stream>>>(spx, spy, spz, perm, x1x, x1y, x1z);
  k_fps2<<<1, F2T, 0, stream>>>(x1x, x1y, x1z, x2x, x2y, x2z);
  k_ballq<<<512, 256, 0, stream>>>(xx, xy, xz, N_PTS, x1x, x1y, x1z, NP1, R2A, NSAMP1, gidx1);
  k_ballq<<<128, 256, 0, stream>>>(x1x, x1y, x1z, NP1, x2x, x2y, x2z, NP2, R2B, NSAMP2, gidx2);

  // SA1: 65536 rows in 8 chunks of 8192 (s-chunks of 256)
  for (int ch = 0; ch < 8; ++ch) {
    int rbase = ch * 8192;
    k_gather1<<<32, 256, 0, stream>>>(pts, prop, xx, xy, xz, x1x, x1y, x1z, gidx1, Xp, rbase);
    k_gemm<<<dim3(1, 128), 256, 0, stream>>>(Xp, w[0][0], b[0][0], Ha, 8192, 64, 15);
    k_gemm<<<dim3(1, 128), 256, 0, stream>>>(Ha, w[0][1], b[0][1], Hb, 8192, 64, 64);
    k_gemm<<<dim3(2, 128), 256, 0, stream>>>(Hb, w[0][2], b[0][2], Hc, 8192, 128, 64);
    k_maxpool<<<128, 256, 0, stream>>>(Hc, f1, 256, 32, 128, ch * 256);
  }

  // SA2: 32768 rows in 4 chunks of 8192 (s-chunks of 128)
  for (int ch = 0; ch < 4; ++ch) {
    int rbase = ch * 8192;
    k_gather2<<<(8192 * 131 + 255) / 256, 256, 0, stream>>>(x1x, x1y, x1z, x2x, x2y, x2z,
                                                            gidx2, f1, Xp, rbase);
    k_gemm<<<dim3(2, 128), 256, 0, stream>>>(Xp, w[1][0], b[1][0], Ha, 8192, 128, 131);
    k_gemm<<<dim3(2, 128), 256, 0, stream>>>(Ha, w[1][1], b[1][1], Hb, 8192, 128, 128);
    k_gemm<<<dim3(4, 128), 256, 0, stream>>>(Hb, w[1][2], b[1][2], Hc, 8192, 256, 128);
    k_maxpool<<<128, 256, 0, stream>>>(Hc, f2, 128, 64, 256, ch * 128);
  }

  // SA3
  k_gather3<<<(512 * 259 + 255) / 256, 256, 0, stream>>>(x2x, x2y, x2z, f2, Xp);
  k_gemm<<<dim3(4, 8), 256, 0, stream>>>(Xp, w[2][0], b[2][0], Ha, 512, 256, 259);
  k_gemm<<<dim3(8, 8), 256, 0, stream>>>(Ha, w[2][1], b[2][1], Hb, 512, 512, 256);
  k_gemm<<<dim3(16, 8), 256, 0, stream>>>(Hb, w[2][2], b[2][2], Hc, 512, 1024, 512);
  k_maxpool<<<4, 256, 0, stream>>>(Hc, (float*)d_out, 1, 512, 1024, 0);
}

// Round 13
// 5749.471 us; speedup vs baseline: 1.6156x; 1.6156x over previous
//
#include <hip/hip_runtime.h>
#include <cstdint>
#include <cstddef>

typedef unsigned long long ull;

#define N_PTS  32768
#define NP1    2048
#define NSAMP1 32
#define NP2    512
#define NSAMP2 64

// ---------------- prep: xyz = points - [x,y,0], SoA ----------------
__global__ __launch_bounds__(256) void k_prep(const float* __restrict__ pts,
                                              const float* __restrict__ prop,
                                              float* __restrict__ xx,
                                              float* __restrict__ xy,
                                              float* __restrict__ xz) {
  int t = blockIdx.x * 256 + threadIdx.x;
  if (t >= N_PTS) return;
  float x = prop[0], y = prop[1];
  xx[t] = __fsub_rn(pts[3 * t + 0], x);
  xy[t] = __fsub_rn(pts[3 * t + 1], y);
  xz[t] = pts[3 * t + 2];
}

// ---------------- FPS1: 2048 of 32768, single persistent block ----------------
// R13: VERBATIM revert to the R4 kernel (measured 4558us twice). The R5-R12
// exploration is closed: three independent pruning implementations (R7 thread-
// bbox, R8 LDS-publish, R12 wave-uniform) all landed 1.7-2x SLOWER than the
// full update — the 16 waves' update VALU is itself the latency hider for the
// per-iter serial chain (barrier + wmax chain + atomicMin + centroid loads);
// removing work below that floor only exposes it (~4us/iter raw). Multi-block
// (R11) is pinned by the ~2us cross-XCD store->poll round trip. This structure
// = the measured optimum: 1024 thr x 32 pts, z in LDS (128KB, chunk-XOR
// swizzle -> conflict-cheap ds_read_b128), px/py/d in regs+AGPR under the
// allocator's hard 64-VGPR cap (65536/threads, attribute-proof), 2 barriers,
// wmax LDS array + atomicMin double-buffered winner slot.
#define F1T 1024
#define F1P 32

__global__
__attribute__((amdgpu_flat_work_group_size(F1T, F1T)))
void k_fps1(const float* __restrict__ xx,
            const float* __restrict__ xy,
            const float* __restrict__ xz,
            float* __restrict__ ox,
            float* __restrict__ oy,
            float* __restrict__ oz) {
  __shared__ __align__(16) float zl[F1P * F1T];   // 128 KB, swizzled row-per-thread
  __shared__ float wmax[F1T / 64];                // 16 per-wave maxima
  __shared__ int S[2];                            // double-buffered winner index
  int tid = threadIdx.x;
  char* zb = (char*)zl;
  // row base with the tid-dependent swizzle term folded in (bits 4-6 disjoint
  // from tid*128, so base ^ (c*16) == tid*128 + ((tid&7)^c)*16)
  int rowb = tid * 128 + (tid & 7) * 16;
  float px[F1P], py[F1P], d[F1P];
#pragma unroll
  for (int s = 0; s < F1P; ++s) {
    int i = s * F1T + tid;                        // point-major: coalesced
    px[s] = xx[i];
    py[s] = xy[i];
    float z = xz[i];
    *(float*)(zb + ((rowb ^ ((s >> 2) * 16)) + (s & 3) * 4)) = z;
    d[s] = 1e10f;
  }
  if (tid == 0) { S[0] = 0; S[1] = 0x7fffffff; }
  __syncthreads();
  for (int it = 0; it < NP1; ++it) {
    int f = __builtin_amdgcn_readfirstlane(S[it & 1]);
    float cx = xx[f], cy = xy[f], cz = xz[f];
    if (tid == 0) { ox[it] = cx; oy[it] = cy; oz[it] = cz; }
    float bestv = -1.0f;
#pragma unroll
    for (int c = 0; c < 8; ++c) {
      const float4 zz = *(const float4*)(zb + (rowb ^ (c * 16)));  // ds_read_b128, conflict-free
      float zv[4] = {zz.x, zz.y, zz.z, zz.w};
#pragma unroll
      for (int j = 0; j < 4; ++j) {
        int s = c * 4 + j;
        // exact reference arithmetic: no fma, (dx^2 + dy^2) + dz^2
        float dx = __fsub_rn(px[s], cx);
        float dy = __fsub_rn(py[s], cy);
        float dz = __fsub_rn(zv[j], cz);
        float d2 = __fadd_rn(__fadd_rn(__fmul_rn(dx, dx), __fmul_rn(dy, dy)), __fmul_rn(dz, dz));
        float dn = fminf(d[s], d2);
        d[s] = dn;
        bestv = fmaxf(bestv, dn);
      }
    }
    float wv = bestv;
#pragma unroll
    for (int m = 1; m < 64; m <<= 1) wv = fmaxf(wv, __shfl_xor(wv, m, 64));
    if ((tid & 63) == 0) wmax[tid >> 6] = wv;
    __syncthreads();                         // (A) wmax ready; all reads of S[it&1] done
    float gb = wmax[0];
#pragma unroll
    for (int k = 1; k < F1T / 64; ++k) gb = fmaxf(gb, wmax[k]);
    if (bestv == gb) {                       // only waves holding a global max pay the scan
      int cand = 0x7fffffff;
#pragma unroll
      for (int s = F1P - 1; s >= 0; --s) cand = (d[s] == gb) ? (s * F1T + tid) : cand;
      atomicMin(&S[(it + 1) & 1], cand);     // max value is a selection -> bitwise match exists
    }
    if (tid == 0) S[it & 1] = 0x7fffffff;    // reset: becomes dst at it+1
    __syncthreads();                         // (B) winner final
  }
}

// ---------------- FPS2: 512 of 2048, single block, 512 threads x 4 pts ----------------
#define F2T 512
#define F2P 4
__global__ __launch_bounds__(F2T, 1) void k_fps2(const float* __restrict__ x1x,
                                                 const float* __restrict__ x1y,
                                                 const float* __restrict__ x1z,
                                                 float* __restrict__ ox,
                                                 float* __restrict__ oy,
                                                 float* __restrict__ oz) {
  __shared__ float sx[NP1], sy[NP1], sz[NP1];   // 24 KB: centroid reads become LDS broadcast
  __shared__ float wmax[F2T / 64];
  __shared__ int S[2];
  int tid = threadIdx.x;
  float px[F2P], py[F2P], pz[F2P], d[F2P];
#pragma unroll
  for (int s = 0; s < F2P; ++s) {
    int i = s * F2T + tid;
    px[s] = x1x[i]; py[s] = x1y[i]; pz[s] = x1z[i];
    sx[i] = px[s];  sy[i] = py[s];  sz[i] = pz[s];
    d[s] = 1e10f;
  }
  if (tid == 0) { S[0] = 0; S[1] = 0x7fffffff; }
  __syncthreads();
  for (int it = 0; it < NP2; ++it) {
    int f = __builtin_amdgcn_readfirstlane(S[it & 1]);
    float cx = sx[f], cy = sy[f], cz = sz[f];  // LDS broadcast
    if (tid == 0) { ox[it] = cx; oy[it] = cy; oz[it] = cz; }
    float bestv = -1.0f;
#pragma unroll
    for (int s = 0; s < F2P; ++s) {
      float dx = __fsub_rn(px[s], cx);
      float dy = __fsub_rn(py[s], cy);
      float dz = __fsub_rn(pz[s], cz);
      float d2 = __fadd_rn(__fadd_rn(__fmul_rn(dx, dx), __fmul_rn(dy, dy)), __fmul_rn(dz, dz));
      float dn = fminf(d[s], d2);
      d[s] = dn;
      bestv = fmaxf(bestv, dn);
    }
    float wv = bestv;
#pragma unroll
    for (int m = 1; m < 64; m <<= 1) wv = fmaxf(wv, __shfl_xor(wv, m, 64));
    if ((tid & 63) == 0) wmax[tid >> 6] = wv;
    __syncthreads();                         // (A)
    float gb = wmax[0];
#pragma unroll
    for (int k = 1; k < F2T / 64; ++k) gb = fmaxf(gb, wmax[k]);
    if (bestv == gb) {
      int cand = 0x7fffffff;
#pragma unroll
      for (int s = F2P - 1; s >= 0; --s) cand = (d[s] == gb) ? (s * F2T + tid) : cand;
      atomicMin(&S[(it + 1) & 1], cand);
    }
    if (tid == 0) S[it & 1] = 0x7fffffff;
    __syncthreads();                         // (B)
  }
}

// ---------------- ball query: first ns indices (ascending) within r2, pad with first ----------------
__global__ void k_ballq(const float* __restrict__ px, const float* __restrict__ py,
                        const float* __restrict__ pz, int n,
                        const float* __restrict__ qx, const float* __restrict__ qy,
                        const float* __restrict__ qz, int S,
                        float r2, int ns, int* __restrict__ out) {
  int w = (blockIdx.x * (int)blockDim.x + threadIdx.x) >> 6;  // one wave per query
  int lane = threadIdx.x & 63;
  if (w >= S) return;
  float cx = qx[w], cy = qy[w], cz = qz[w];
  int found = 0, first = 0;
  bool havefirst = false;
  for (int base = 0; base < n && found < ns; base += 64) {
    int i = base + lane;
    float dx = __fsub_rn(px[i], cx);
    float dy = __fsub_rn(py[i], cy);
    float dz = __fsub_rn(pz[i], cz);
    float d2 = __fadd_rn(__fadd_rn(__fmul_rn(dx, dx), __fmul_rn(dy, dy)), __fmul_rn(dz, dz));
    bool isin = d2 <= r2;
    ull m = __ballot(isin);
    if (!havefirst && m != 0ull) { first = base + __builtin_ctzll(m); havefirst = true; }
    if (isin) {
      int r = (int)__popcll(m & ((1ull << lane) - 1ull));
      int slot = found + r;
      if (slot < ns) out[w * ns + slot] = i;
    }
    found += (int)__popcll(m);
  }
  for (int s2 = found + lane; s2 < ns; s2 += 64) out[w * ns + s2] = first;
}

// ---------------- gather SA1 input rows (15 ch), nrows per chunk ----------------
__global__ __launch_bounds__(256) void k_gather1(const float* __restrict__ pts,
                                                 const float* __restrict__ prop,
                                                 const float* __restrict__ xx,
                                                 const float* __restrict__ xy,
                                                 const float* __restrict__ xz,
                                                 const float* __restrict__ x1x,
                                                 const float* __restrict__ x1y,
                                                 const float* __restrict__ x1z,
                                                 const int* __restrict__ gidx,
                                                 float* __restrict__ X, int rbase, int nrows) {
  int rl = blockIdx.x * 256 + threadIdx.x;
  if (rl >= nrows) return;
  int r = rbase + rl;
  int s = r >> 5;
  int g = gidx[r];
  float x = prop[0], y = prop[1], wz = prop[3];
  float w2 = wz * 0.5f;  // == w/2 exactly
  float oxp = __fadd_rn(x, w2), oxm = __fsub_rn(x, w2);
  float oyp = __fadd_rn(y, w2), oym = __fsub_rn(y, w2);
  float gx = xx[g], gy = xy[g], gz = xz[g];
  float pxv = pts[3 * g + 0], pyv = pts[3 * g + 1];
  float* o = X + (size_t)rl * 15;
  o[0] = __fsub_rn(gx, x1x[s]);
  o[1] = __fsub_rn(gy, x1y[s]);
  o[2] = __fsub_rn(gz, x1z[s]);
  o[3] = __fsub_rn(pxv, oxp);  o[4]  = gy;                    o[5]  = gz;
  o[6] = __fsub_rn(pxv, oxm);  o[7]  = gy;                    o[8]  = gz;
  o[9] = gx;                   o[10] = __fsub_rn(pyv, oyp);   o[11] = gz;
  o[12] = gx;                  o[13] = __fsub_rn(pyv, oym);   o[14] = gz;
}

// ---------------- gather SA2 input rows (131 ch), element-parallel ----------------
__global__ __launch_bounds__(256) void k_gather2(const float* __restrict__ x1x,
                                                 const float* __restrict__ x1y,
                                                 const float* __restrict__ x1z,
                                                 const float* __restrict__ x2x,
                                                 const float* __restrict__ x2y,
                                                 const float* __restrict__ x2z,
                                                 const int* __restrict__ gidx,
                                                 const float* __restrict__ f1,
                                                 float* __restrict__ X, int rbase) {
  int e = blockIdx.x * 256 + threadIdx.x;
  if (e >= 8192 * 131) return;
  int rl = e / 131, c = e % 131;
  int r = rbase + rl;
  int s = r >> 6;
  int g = gidx[r];
  float v;
  if (c == 0)      v = __fsub_rn(x1x[g], x2x[s]);
  else if (c == 1) v = __fsub_rn(x1y[g], x2y[s]);
  else if (c == 2) v = __fsub_rn(x1z[g], x2z[s]);
  else             v = f1[(size_t)g * 128 + (c - 3)];
  X[e] = v;
}

// ---------------- gather SA3 input rows (259 ch) ----------------
__global__ __launch_bounds__(256) void k_gather3(const float* __restrict__ x2x,
                                                 const float* __restrict__ x2y,
                                                 const float* __restrict__ x2z,
                                                 const float* __restrict__ f2,
                                                 float* __restrict__ X) {
  int e = blockIdx.x * 256 + threadIdx.x;
  if (e >= 512 * 259) return;
  int rl = e / 259, c = e % 259;
  float v;
  if (c == 0)      v = x2x[rl];
  else if (c == 1) v = x2y[rl];
  else if (c == 2) v = x2z[rl];
  else             v = f2[(size_t)rl * 256 + (c - 3)];
  X[e] = v;
}

// ---------------- relu GEMM: C[m][n] = relu(bias[n] + sum_k A[m,k]*W[n,k]) ----------------
// 64x64 tile, 256 threads, 4x4 per thread, transposed LDS staging for b128 reads
__global__ __launch_bounds__(256) void k_gemm(const float* __restrict__ A,
                                              const float* __restrict__ W,
                                              const float* __restrict__ bias,
                                              float* __restrict__ C,
                                              int M, int N, int K) {
  __shared__ __align__(16) float As[16][68];
  __shared__ __align__(16) float Bs[16][68];
  int tid = threadIdx.x;
  int bn = blockIdx.x * 64, bm = blockIdx.y * 64;
  int tx = tid & 15, ty = tid >> 4;
  float acc[4][4] = {{0.f, 0.f, 0.f, 0.f}, {0.f, 0.f, 0.f, 0.f},
                     {0.f, 0.f, 0.f, 0.f}, {0.f, 0.f, 0.f, 0.f}};
  for (int k0 = 0; k0 < K; k0 += 16) {
#pragma unroll
    for (int e = 0; e < 4; ++e) {
      int flat = tid + e * 256;
      int rr = flat >> 4, cc = flat & 15;
      As[cc][rr] = (k0 + cc < K) ? A[(size_t)(bm + rr) * K + (k0 + cc)] : 0.0f;
      Bs[cc][rr] = (k0 + cc < K) ? W[(size_t)(bn + rr) * K + (k0 + cc)] : 0.0f;
    }
    __syncthreads();
#pragma unroll
    for (int kk = 0; kk < 16; ++kk) {
      const float4 a = *(const float4*)&As[kk][ty * 4];
      const float4 b = *(const float4*)&Bs[kk][tx * 4];
      float av[4] = {a.x, a.y, a.z, a.w};
      float bb[4] = {b.x, b.y, b.z, b.w};
#pragma unroll
      for (int i = 0; i < 4; ++i)
#pragma unroll
        for (int j = 0; j < 4; ++j)
          acc[i][j] = fmaf(av[i], bb[j], acc[i][j]);
    }
    __syncthreads();
  }
#pragma unroll
  for (int i = 0; i < 4; ++i) {
    int m = bm + ty * 4 + i;
    float4 o;
    o.x = fmaxf(acc[i][0] + bias[bn + tx * 4 + 0], 0.0f);
    o.y = fmaxf(acc[i][1] + bias[bn + tx * 4 + 1], 0.0f);
    o.z = fmaxf(acc[i][2] + bias[bn + tx * 4 + 2], 0.0f);
    o.w = fmaxf(acc[i][3] + bias[bn + tx * 4 + 3], 0.0f);
    *(float4*)&C[(size_t)m * N + bn + tx * 4] = o;
  }
}

// ---------------- maxpool over Ks consecutive rows ----------------
__global__ __launch_bounds__(256) void k_maxpool(const float* __restrict__ H,
                                                 float* __restrict__ F,
                                                 int S, int Ks, int Nch, int sbase) {
  int t = blockIdx.x * 256 + threadIdx.x;
  if (t >= S * Nch) return;
  int sl = t / Nch, n = t % Nch;
  const float* p = H + (size_t)sl * Ks * Nch + n;
  float m = p[0];
  for (int k = 1; k < Ks; ++k) m = fmaxf(m, p[(size_t)k * Nch]);
  F[(size_t)(sbase + sl) * Nch + n] = m;
}

// ---------------- host ----------------
extern "C" void kernel_launch(void* const* d_in, const int* in_sizes, int n_in,
                              void* d_out, int out_size, void* d_ws, size_t ws_size,
                              hipStream_t stream) {
  (void)n_in; (void)out_size; (void)ws_size;
  const float* pts = (const float*)d_in[0];
  const float* prop = (const float*)d_in[1];

  // inputs may arrive in dict order (w0,b0,w1,b1,w2,b2) or signature order (w0,w1,w2,b0,b1,b2)
  bool dict_order = (in_sizes[3] == 64);
  const float *w[3][3], *b[3][3];
  for (int g = 0; g < 3; ++g)
    for (int l = 0; l < 3; ++l) {
      int base = 2 + g * 6;
      int wi = dict_order ? (base + l * 2) : (base + l);
      int bi = dict_order ? (base + l * 2 + 1) : (base + 3 + l);
      w[g][l] = (const float*)d_in[wi];
      b[g][l] = (const float*)d_in[bi];
    }

  float* ws = (float*)d_ws;
  float* xx = ws;
  float* xy = xx + N_PTS;
  float* xz = xy + N_PTS;
  float* x1x = xz + N_PTS;
  float* x1y = x1x + NP1;
  float* x1z = x1y + NP1;
  float* x2x = x1z + NP1;
  float* x2y = x2x + NP2;
  float* x2z = x2y + NP2;
  int* gidx1 = (int*)(x2z + NP2);            // 2048*32
  int* gidx2 = gidx1 + NP1 * NSAMP1;         // 512*64
  float* f1 = (float*)(gidx2 + NP2 * NSAMP2);// 2048*128
  float* f2 = f1 + NP1 * 128;                // 512*256
  float* Xp = f2 + NP2 * 256;                // 8192*131 pool (also 16384*15, 512*259)
  float* Ha = Xp + 8192 * 131;               // 8192*128 pool (= 16384*64 exactly)
  float* Hb = Ha + 8192 * 128;               // 8192*128 pool (= 16384*64 exactly)
  float* Hc = Hb + 8192 * 128;               // 8192*256 pool (= 16384*128 exactly; also 512*1024)

  const float R2A = (float)(0.4 * 0.4);  // f32 of python-f64 product: 1 ulp below 0.4f*0.4f
  const float R2B = (float)(0.8 * 0.8);

  k_prep<<<128, 256, 0, stream>>>(pts, prop, xx, xy, xz);
  k_fps1<<<1, F1T, 0, stream>>>(xx, xy, xz, x1x, x1y, x1z);
  k_fps2<<<1, F2T, 0, stream>>>(x1x, x1y, x1z, x2x, x2y, x2z);
  k_ballq<<<512, 256, 0, stream>>>(xx, xy, xz, N_PTS, x1x, x1y, x1z, NP1, R2A, NSAMP1, gidx1);
  k_ballq<<<128, 256, 0, stream>>>(x1x, x1y, x1z, NP1, x2x, x2y, x2z, NP2, R2B, NSAMP2, gidx2);

  // SA1: 65536 rows in 4 chunks of 16384 (s-chunks of 512). Pools fit exactly:
  // X 16384*15 <= Xp(1.07M fl); Ha/Hb 16384*64 = pool; Hc 16384*128 = pool.
  // vs R4's 8x8192: halves launch count AND fills all 256 CUs (gemm y-blocks
  // 128 -> 256).
  for (int ch = 0; ch < 4; ++ch) {
    int rbase = ch * 16384;
    k_gather1<<<64, 256, 0, stream>>>(pts, prop, xx, xy, xz, x1x, x1y, x1z, gidx1, Xp, rbase, 16384);
    k_gemm<<<dim3(1, 256), 256, 0, stream>>>(Xp, w[0][0], b[0][0], Ha, 16384, 64, 15);
    k_gemm<<<dim3(1, 256), 256, 0, stream>>>(Ha, w[0][1], b[0][1], Hb, 16384, 64, 64);
    k_gemm<<<dim3(2, 256), 256, 0, stream>>>(Hb, w[0][2], b[0][2], Hc, 16384, 128, 64);
    k_maxpool<<<256, 256, 0, stream>>>(Hc, f1, 512, 32, 128, ch * 512);
  }

  // SA2: 32768 rows in 4 chunks of 8192 (s-chunks of 128) — pools exactly fit, unchanged
  for (int ch = 0; ch < 4; ++ch) {
    int rbase = ch * 8192;
    k_gather2<<<(8192 * 131 + 255) / 256, 256, 0, stream>>>(x1x, x1y, x1z, x2x, x2y, x2z,
                                                            gidx2, f1, Xp, rbase);
    k_gemm<<<dim3(2, 128), 256, 0, stream>>>(Xp, w[1][0], b[1][0], Ha, 8192, 128, 131);
    k_gemm<<<dim3(2, 128), 256, 0, stream>>>(Ha, w[1][1], b[1][1], Hb, 8192, 128, 128);
    k_gemm<<<dim3(4, 128), 256, 0, stream>>>(Hb, w[1][2], b[1][2], Hc, 8192, 256, 128);
    k_maxpool<<<128, 256, 0, stream>>>(Hc, f2, 128, 64, 256, ch * 128);
  }

  // SA3
  k_gather3<<<(512 * 259 + 255) / 256, 256, 0, stream>>>(x2x, x2y, x2z, f2, Xp);
  k_gemm<<<dim3(4, 8), 256, 0, stream>>>(Xp, w[2][0], b[2][0], Ha, 512, 256, 259);
  k_gemm<<<dim3(8, 8), 256, 0, stream>>>(Ha, w[2][1], b[2][1], Hb, 512, 512, 256);
  k_gemm<<<dim3(16, 8), 256, 0, stream>>>(Hb, w[2][2], b[2][2], Hc, 512, 1024, 512);
  k_maxpool<<<4, 256, 0, stream>>>(Hc, (float*)d_out, 1, 512, 1024, 0);
}

// Round 14
// 5462.089 us; speedup vs baseline: 1.7006x; 1.0526x over previous
//
#include <hip/hip_runtime.h>
#include <cstdint>
#include <cstddef>

typedef unsigned long long ull;

#define N_PTS  32768
#define NP1    2048
#define NSAMP1 32
#define NP2    512
#define NSAMP2 64

// ---------------- prep: xyz = points - [x,y,0], SoA ----------------
__global__ __launch_bounds__(256) void k_prep(const float* __restrict__ pts,
                                              const float* __restrict__ prop,
                                              float* __restrict__ xx,
                                              float* __restrict__ xy,
                                              float* __restrict__ xz) {
  int t = blockIdx.x * 256 + threadIdx.x;
  if (t >= N_PTS) return;
  float x = prop[0], y = prop[1];
  xx[t] = __fsub_rn(pts[3 * t + 0], x);
  xy[t] = __fsub_rn(pts[3 * t + 1], y);
  xz[t] = pts[3 * t + 2];
}

// ---------------- FPS1: 2048 of 32768, single persistent block ----------------
// FROZEN (R13 verbatim = R4 structure, measured 4558/4568/4588us across three
// sessions). R5-R12 exploration closed: pruning (3 variants), multi-block, and
// packed/atomic reduce variants all regressed — the 16 waves' update VALU is
// itself the latency hider for the per-iter serial chain. Do not touch.
#define F1T 1024
#define F1P 32

__global__
__attribute__((amdgpu_flat_work_group_size(F1T, F1T)))
void k_fps1(const float* __restrict__ xx,
            const float* __restrict__ xy,
            const float* __restrict__ xz,
            float* __restrict__ ox,
            float* __restrict__ oy,
            float* __restrict__ oz) {
  __shared__ __align__(16) float zl[F1P * F1T];   // 128 KB, swizzled row-per-thread
  __shared__ float wmax[F1T / 64];                // 16 per-wave maxima
  __shared__ int S[2];                            // double-buffered winner index
  int tid = threadIdx.x;
  char* zb = (char*)zl;
  int rowb = tid * 128 + (tid & 7) * 16;
  float px[F1P], py[F1P], d[F1P];
#pragma unroll
  for (int s = 0; s < F1P; ++s) {
    int i = s * F1T + tid;                        // point-major: coalesced
    px[s] = xx[i];
    py[s] = xy[i];
    float z = xz[i];
    *(float*)(zb + ((rowb ^ ((s >> 2) * 16)) + (s & 3) * 4)) = z;
    d[s] = 1e10f;
  }
  if (tid == 0) { S[0] = 0; S[1] = 0x7fffffff; }
  __syncthreads();
  for (int it = 0; it < NP1; ++it) {
    int f = __builtin_amdgcn_readfirstlane(S[it & 1]);
    float cx = xx[f], cy = xy[f], cz = xz[f];
    if (tid == 0) { ox[it] = cx; oy[it] = cy; oz[it] = cz; }
    float bestv = -1.0f;
#pragma unroll
    for (int c = 0; c < 8; ++c) {
      const float4 zz = *(const float4*)(zb + (rowb ^ (c * 16)));  // ds_read_b128
      float zv[4] = {zz.x, zz.y, zz.z, zz.w};
#pragma unroll
      for (int j = 0; j < 4; ++j) {
        int s = c * 4 + j;
        // exact reference arithmetic: no fma, (dx^2 + dy^2) + dz^2
        float dx = __fsub_rn(px[s], cx);
        float dy = __fsub_rn(py[s], cy);
        float dz = __fsub_rn(zv[j], cz);
        float d2 = __fadd_rn(__fadd_rn(__fmul_rn(dx, dx), __fmul_rn(dy, dy)), __fmul_rn(dz, dz));
        float dn = fminf(d[s], d2);
        d[s] = dn;
        bestv = fmaxf(bestv, dn);
      }
    }
    float wv = bestv;
#pragma unroll
    for (int m = 1; m < 64; m <<= 1) wv = fmaxf(wv, __shfl_xor(wv, m, 64));
    if ((tid & 63) == 0) wmax[tid >> 6] = wv;
    __syncthreads();                         // (A) wmax ready; all reads of S[it&1] done
    float gb = wmax[0];
#pragma unroll
    for (int k = 1; k < F1T / 64; ++k) gb = fmaxf(gb, wmax[k]);
    if (bestv == gb) {                       // only waves holding a global max pay the scan
      int cand = 0x7fffffff;
#pragma unroll
      for (int s = F1P - 1; s >= 0; --s) cand = (d[s] == gb) ? (s * F1T + tid) : cand;
      atomicMin(&S[(it + 1) & 1], cand);     // max value is a selection -> bitwise match exists
    }
    if (tid == 0) S[it & 1] = 0x7fffffff;    // reset: becomes dst at it+1
    __syncthreads();                         // (B) winner final
  }
}

// ---------------- FPS2: 512 of 2048, single block, 512 threads x 4 pts ----------------
#define F2T 512
#define F2P 4
__global__ __launch_bounds__(F2T, 1) void k_fps2(const float* __restrict__ x1x,
                                                 const float* __restrict__ x1y,
                                                 const float* __restrict__ x1z,
                                                 float* __restrict__ ox,
                                                 float* __restrict__ oy,
                                                 float* __restrict__ oz) {
  __shared__ float sx[NP1], sy[NP1], sz[NP1];   // 24 KB: centroid reads become LDS broadcast
  __shared__ float wmax[F2T / 64];
  __shared__ int S[2];
  int tid = threadIdx.x;
  float px[F2P], py[F2P], pz[F2P], d[F2P];
#pragma unroll
  for (int s = 0; s < F2P; ++s) {
    int i = s * F2T + tid;
    px[s] = x1x[i]; py[s] = x1y[i]; pz[s] = x1z[i];
    sx[i] = px[s];  sy[i] = py[s];  sz[i] = pz[s];
    d[s] = 1e10f;
  }
  if (tid == 0) { S[0] = 0; S[1] = 0x7fffffff; }
  __syncthreads();
  for (int it = 0; it < NP2; ++it) {
    int f = __builtin_amdgcn_readfirstlane(S[it & 1]);
    float cx = sx[f], cy = sy[f], cz = sz[f];  // LDS broadcast
    if (tid == 0) { ox[it] = cx; oy[it] = cy; oz[it] = cz; }
    float bestv = -1.0f;
#pragma unroll
    for (int s = 0; s < F2P; ++s) {
      float dx = __fsub_rn(px[s], cx);
      float dy = __fsub_rn(py[s], cy);
      float dz = __fsub_rn(pz[s], cz);
      float d2 = __fadd_rn(__fadd_rn(__fmul_rn(dx, dx), __fmul_rn(dy, dy)), __fmul_rn(dz, dz));
      float dn = fminf(d[s], d2);
      d[s] = dn;
      bestv = fmaxf(bestv, dn);
    }
    float wv = bestv;
#pragma unroll
    for (int m = 1; m < 64; m <<= 1) wv = fmaxf(wv, __shfl_xor(wv, m, 64));
    if ((tid & 63) == 0) wmax[tid >> 6] = wv;
    __syncthreads();                         // (A)
    float gb = wmax[0];
#pragma unroll
    for (int k = 1; k < F2T / 64; ++k) gb = fmaxf(gb, wmax[k]);
    if (bestv == gb) {
      int cand = 0x7fffffff;
#pragma unroll
      for (int s = F2P - 1; s >= 0; --s) cand = (d[s] == gb) ? (s * F2T + tid) : cand;
      atomicMin(&S[(it + 1) & 1], cand);
    }
    if (tid == 0) S[it & 1] = 0x7fffffff;
    __syncthreads();                         // (B)
  }
}

// ---------------- ball query: first ns indices (ascending) within r2, pad with first ----------------
__global__ void k_ballq(const float* __restrict__ px, const float* __restrict__ py,
                        const float* __restrict__ pz, int n,
                        const float* __restrict__ qx, const float* __restrict__ qy,
                        const float* __restrict__ qz, int S,
                        float r2, int ns, int* __restrict__ out) {
  int w = (blockIdx.x * (int)blockDim.x + threadIdx.x) >> 6;  // one wave per query
  int lane = threadIdx.x & 63;
  if (w >= S) return;
  float cx = qx[w], cy = qy[w], cz = qz[w];
  int found = 0, first = 0;
  bool havefirst = false;
  for (int base = 0; base < n && found < ns; base += 64) {
    int i = base + lane;
    float dx = __fsub_rn(px[i], cx);
    float dy = __fsub_rn(py[i], cy);
    float dz = __fsub_rn(pz[i], cz);
    float d2 = __fadd_rn(__fadd_rn(__fmul_rn(dx, dx), __fmul_rn(dy, dy)), __fmul_rn(dz, dz));
    bool isin = d2 <= r2;
    ull m = __ballot(isin);
    if (!havefirst && m != 0ull) { first = base + __builtin_ctzll(m); havefirst = true; }
    if (isin) {
      int r = (int)__popcll(m & ((1ull << lane) - 1ull));
      int slot = found + r;
      if (slot < ns) out[w * ns + slot] = i;
    }
    found += (int)__popcll(m);
  }
  for (int s2 = found + lane; s2 < ns; s2 += 64) out[w * ns + s2] = first;
}

// ---------------- gather SA1 input rows (15 ch), nrows per chunk ----------------
__global__ __launch_bounds__(256) void k_gather1(const float* __restrict__ pts,
                                                 const float* __restrict__ prop,
                                                 const float* __restrict__ xx,
                                                 const float* __restrict__ xy,
                                                 const float* __restrict__ xz,
                                                 const float* __restrict__ x1x,
                                                 const float* __restrict__ x1y,
                                                 const float* __restrict__ x1z,
                                                 const int* __restrict__ gidx,
                                                 float* __restrict__ X, int rbase, int nrows) {
  int rl = blockIdx.x * 256 + threadIdx.x;
  if (rl >= nrows) return;
  int r = rbase + rl;
  int s = r >> 5;
  int g = gidx[r];
  float x = prop[0], y = prop[1], wz = prop[3];
  float w2 = wz * 0.5f;  // == w/2 exactly
  float oxp = __fadd_rn(x, w2), oxm = __fsub_rn(x, w2);
  float oyp = __fadd_rn(y, w2), oym = __fsub_rn(y, w2);
  float gx = xx[g], gy = xy[g], gz = xz[g];
  float pxv = pts[3 * g + 0], pyv = pts[3 * g + 1];
  float* o = X + (size_t)rl * 15;
  o[0] = __fsub_rn(gx, x1x[s]);
  o[1] = __fsub_rn(gy, x1y[s]);
  o[2] = __fsub_rn(gz, x1z[s]);
  o[3] = __fsub_rn(pxv, oxp);  o[4]  = gy;                    o[5]  = gz;
  o[6] = __fsub_rn(pxv, oxm);  o[7]  = gy;                    o[8]  = gz;
  o[9] = gx;                   o[10] = __fsub_rn(pyv, oyp);   o[11] = gz;
  o[12] = gx;                  o[13] = __fsub_rn(pyv, oym);   o[14] = gz;
}

// ---------------- gather SA2 input rows (131 ch), element-parallel ----------------
__global__ __launch_bounds__(256) void k_gather2(const float* __restrict__ x1x,
                                                 const float* __restrict__ x1y,
                                                 const float* __restrict__ x1z,
                                                 const float* __restrict__ x2x,
                                                 const float* __restrict__ x2y,
                                                 const float* __restrict__ x2z,
                                                 const int* __restrict__ gidx,
                                                 const float* __restrict__ f1,
                                                 float* __restrict__ X, int rbase, int nelem) {
  int e = blockIdx.x * 256 + threadIdx.x;
  if (e >= nelem) return;
  int rl = e / 131, c = e % 131;
  int r = rbase + rl;
  int s = r >> 6;
  int g = gidx[r];
  float v;
  if (c == 0)      v = __fsub_rn(x1x[g], x2x[s]);
  else if (c == 1) v = __fsub_rn(x1y[g], x2y[s]);
  else if (c == 2) v = __fsub_rn(x1z[g], x2z[s]);
  else             v = f1[(size_t)g * 128 + (c - 3)];
  X[e] = v;
}

// ---------------- gather SA3 input rows (259 ch) ----------------
__global__ __launch_bounds__(256) void k_gather3(const float* __restrict__ x2x,
                                                 const float* __restrict__ x2y,
                                                 const float* __restrict__ x2z,
                                                 const float* __restrict__ f2,
                                                 float* __restrict__ X) {
  int e = blockIdx.x * 256 + threadIdx.x;
  if (e >= 512 * 259) return;
  int rl = e / 259, c = e % 259;
  float v;
  if (c == 0)      v = x2x[rl];
  else if (c == 1) v = x2y[rl];
  else if (c == 2) v = x2z[rl];
  else             v = f2[(size_t)rl * 256 + (c - 3)];
  X[e] = v;
}

// ---------------- relu GEMM: C[m][n] = relu(bias[n] + sum_k A[m,k]*W[n,k]) ----------------
// 64x64 tile, 256 threads, 4x4 per thread, transposed LDS staging for b128 reads
__global__ __launch_bounds__(256) void k_gemm(const float* __restrict__ A,
                                              const float* __restrict__ W,
                                              const float* __restrict__ bias,
                                              float* __restrict__ C,
                                              int M, int N, int K) {
  __shared__ __align__(16) float As[16][68];
  __shared__ __align__(16) float Bs[16][68];
  int tid = threadIdx.x;
  int bn = blockIdx.x * 64, bm = blockIdx.y * 64;
  int tx = tid & 15, ty = tid >> 4;
  float acc[4][4] = {{0.f, 0.f, 0.f, 0.f}, {0.f, 0.f, 0.f, 0.f},
                     {0.f, 0.f, 0.f, 0.f}, {0.f, 0.f, 0.f, 0.f}};
  for (int k0 = 0; k0 < K; k0 += 16) {
#pragma unroll
    for (int e = 0; e < 4; ++e) {
      int flat = tid + e * 256;
      int rr = flat >> 4, cc = flat & 15;
      As[cc][rr] = (k0 + cc < K) ? A[(size_t)(bm + rr) * K + (k0 + cc)] : 0.0f;
      Bs[cc][rr] = (k0 + cc < K) ? W[(size_t)(bn + rr) * K + (k0 + cc)] : 0.0f;
    }
    __syncthreads();
#pragma unroll
    for (int kk = 0; kk < 16; ++kk) {
      const float4 a = *(const float4*)&As[kk][ty * 4];
      const float4 b = *(const float4*)&Bs[kk][tx * 4];
      float av[4] = {a.x, a.y, a.z, a.w};
      float bb[4] = {b.x, b.y, b.z, b.w};
#pragma unroll
      for (int i = 0; i < 4; ++i)
#pragma unroll
        for (int j = 0; j < 4; ++j)
          acc[i][j] = fmaf(av[i], bb[j], acc[i][j]);
    }
    __syncthreads();
  }
#pragma unroll
  for (int i = 0; i < 4; ++i) {
    int m = bm + ty * 4 + i;
    float4 o;
    o.x = fmaxf(acc[i][0] + bias[bn + tx * 4 + 0], 0.0f);
    o.y = fmaxf(acc[i][1] + bias[bn + tx * 4 + 1], 0.0f);
    o.z = fmaxf(acc[i][2] + bias[bn + tx * 4 + 2], 0.0f);
    o.w = fmaxf(acc[i][3] + bias[bn + tx * 4 + 3], 0.0f);
    *(float4*)&C[(size_t)m * N + bn + tx * 4] = o;
  }
}

// ---------------- maxpool over Ks consecutive rows ----------------
__global__ __launch_bounds__(256) void k_maxpool(const float* __restrict__ H,
                                                 float* __restrict__ F,
                                                 int S, int Ks, int Nch, int sbase) {
  int t = blockIdx.x * 256 + threadIdx.x;
  if (t >= S * Nch) return;
  int sl = t / Nch, n = t % Nch;
  const float* p = H + (size_t)sl * Ks * Nch + n;
  float m = p[0];
  for (int k = 1; k < Ks; ++k) m = fmaxf(m, p[(size_t)k * Nch]);
  F[(size_t)(sbase + sl) * Nch + n] = m;
}

// ---------------- host ----------------
extern "C" void kernel_launch(void* const* d_in, const int* in_sizes, int n_in,
                              void* d_out, int out_size, void* d_ws, size_t ws_size,
                              hipStream_t stream) {
  (void)n_in; (void)out_size;
  const float* pts = (const float*)d_in[0];
  const float* prop = (const float*)d_in[1];

  // inputs may arrive in dict order (w0,b0,w1,b1,w2,b2) or signature order (w0,w1,w2,b0,b1,b2)
  bool dict_order = (in_sizes[3] == 64);
  const float *w[3][3], *b[3][3];
  for (int g = 0; g < 3; ++g)
    for (int l = 0; l < 3; ++l) {
      int base = 2 + g * 6;
      int wi = dict_order ? (base + l * 2) : (base + l);
      int bi = dict_order ? (base + l * 2 + 1) : (base + 3 + l);
      w[g][l] = (const float*)d_in[wi];
      b[g][l] = (const float*)d_in[bi];
    }

  // R14: unchunk SA1/SA2 when workspace allows (86.7MB). Chunking existed only
  // for pool sizing; unchunked halves launch count (45->19) and fills all 256
  // CUs (SA1 gemm y-blocks 256->1024, SA2 128->512). Fallback = R13 path.
  bool big = ws_size >= (size_t)87 * 1024 * 1024;
  size_t szX  = big ? (size_t)32768 * 131 : (size_t)8192 * 131;  // 4292608 : 1073152
  size_t szH  = big ? (size_t)65536 * 64  : (size_t)8192 * 128;  // 4194304 : 1048576 (65536*64==32768*128)
  float* ws = (float*)d_ws;
  float* xx = ws;
  float* xy = xx + N_PTS;
  float* xz = xy + N_PTS;
  float* x1x = xz + N_PTS;
  float* x1y = x1x + NP1;
  float* x1z = x1y + NP1;
  float* x2x = x1z + NP1;
  float* x2y = x2x + NP2;
  float* x2z = x2y + NP2;
  int* gidx1 = (int*)(x2z + NP2);            // 2048*32
  int* gidx2 = gidx1 + NP1 * NSAMP1;         // 512*64
  float* f1 = (float*)(gidx2 + NP2 * NSAMP2);// 2048*128
  float* f2 = f1 + NP1 * 128;                // 512*256
  float* Xp = f2 + NP2 * 256;                // input pool
  float* Ha = Xp + szX;                      // H pool a
  float* Hb = Ha + szH;                      // H pool b
  float* Hc = Hb + szH;                      // H pool c (big: 65536*128; small: 8192*256)

  const float R2A = (float)(0.4 * 0.4);  // f32 of python-f64 product: 1 ulp below 0.4f*0.4f
  const float R2B = (float)(0.8 * 0.8);

  k_prep<<<128, 256, 0, stream>>>(pts, prop, xx, xy, xz);
  k_fps1<<<1, F1T, 0, stream>>>(xx, xy, xz, x1x, x1y, x1z);
  k_fps2<<<1, F2T, 0, stream>>>(x1x, x1y, x1z, x2x, x2y, x2z);
  k_ballq<<<512, 256, 0, stream>>>(xx, xy, xz, N_PTS, x1x, x1y, x1z, NP1, R2A, NSAMP1, gidx1);
  k_ballq<<<128, 256, 0, stream>>>(x1x, x1y, x1z, NP1, x2x, x2y, x2z, NP2, R2B, NSAMP2, gidx2);

  if (big) {
    // SA1: one pass over all 65536 rows
    k_gather1<<<256, 256, 0, stream>>>(pts, prop, xx, xy, xz, x1x, x1y, x1z, gidx1, Xp, 0, 65536);
    k_gemm<<<dim3(1, 1024), 256, 0, stream>>>(Xp, w[0][0], b[0][0], Ha, 65536, 64, 15);
    k_gemm<<<dim3(1, 1024), 256, 0, stream>>>(Ha, w[0][1], b[0][1], Hb, 65536, 64, 64);
    k_gemm<<<dim3(2, 1024), 256, 0, stream>>>(Hb, w[0][2], b[0][2], Hc, 65536, 128, 64);
    k_maxpool<<<1024, 256, 0, stream>>>(Hc, f1, 2048, 32, 128, 0);
    // SA2: one pass over all 32768 rows
    k_gather2<<<(32768 * 131 + 255) / 256, 256, 0, stream>>>(x1x, x1y, x1z, x2x, x2y, x2z,
                                                             gidx2, f1, Xp, 0, 32768 * 131);
    k_gemm<<<dim3(2, 512), 256, 0, stream>>>(Xp, w[1][0], b[1][0], Ha, 32768, 128, 131);
    k_gemm<<<dim3(2, 512), 256, 0, stream>>>(Ha, w[1][1], b[1][1], Hb, 32768, 128, 128);
    k_gemm<<<dim3(4, 512), 256, 0, stream>>>(Hb, w[1][2], b[1][2], Hc, 32768, 256, 128);
    k_maxpool<<<512, 256, 0, stream>>>(Hc, f2, 512, 64, 256, 0);
  } else {
    // R13 fallback: SA1 in 4 chunks of 16384 (s-chunks of 512)
    for (int ch = 0; ch < 4; ++ch) {
      int rbase = ch * 16384;
      k_gather1<<<64, 256, 0, stream>>>(pts, prop, xx, xy, xz, x1x, x1y, x1z, gidx1, Xp, rbase, 16384);
      k_gemm<<<dim3(1, 256), 256, 0, stream>>>(Xp, w[0][0], b[0][0], Ha, 16384, 64, 15);
      k_gemm<<<dim3(1, 256), 256, 0, stream>>>(Ha, w[0][1], b[0][1], Hb, 16384, 64, 64);
      k_gemm<<<dim3(2, 256), 256, 0, stream>>>(Hb, w[0][2], b[0][2], Hc, 16384, 128, 64);
      k_maxpool<<<256, 256, 0, stream>>>(Hc, f1, 512, 32, 128, ch * 512);
    }
    // SA2 in 4 chunks of 8192 (s-chunks of 128)
    for (int ch = 0; ch < 4; ++ch) {
      int rbase = ch * 8192;
      k_gather2<<<(8192 * 131 + 255) / 256, 256, 0, stream>>>(x1x, x1y, x1z, x2x, x2y, x2z,
                                                              gidx2, f1, Xp, rbase, 8192 * 131);
      k_gemm<<<dim3(2, 128), 256, 0, stream>>>(Xp, w[1][0], b[1][0], Ha, 8192, 128, 131);
      k_gemm<<<dim3(2, 128), 256, 0, stream>>>(Ha, w[1][1], b[1][1], Hb, 8192, 128, 128);
      k_gemm<<<dim3(4, 128), 256, 0, stream>>>(Hb, w[1][2], b[1][2], Hc, 8192, 256, 128);
      k_maxpool<<<128, 256, 0, stream>>>(Hc, f2, 128, 64, 256, ch * 128);
    }
  }

  // SA3
  k_gather3<<<(512 * 259 + 255) / 256, 256, 0, stream>>>(x2x, x2y, x2z, f2, Xp);
  k_gemm<<<dim3(4, 8), 256, 0, stream>>>(Xp, w[2][0], b[2][0], Ha, 512, 256, 259);
  k_gemm<<<dim3(8, 8), 256, 0, stream>>>(Ha, w[2][1], b[2][1], Hb, 512, 512, 256);
  k_gemm<<<dim3(16, 8), 256, 0, stream>>>(Hb, w[2][2], b[2][2], Hc, 512, 1024, 512);
  k_maxpool<<<4, 256, 0, stream>>>(Hc, (float*)d_out, 1, 512, 1024, 0);
}